// Round 6
// baseline (396.614 us; speedup 1.0000x reference)
//
#include <hip/hip_runtime.h>
#include <hip/hip_bf16.h>
#include <math.h>

// Problem constants
#define NQ1 1001      // NQ+1 rows in embed tables
#define KK 5
#define MM 50
#define KD 64
#define VD 64
#define SD 50
#define BB 512
#define SS 500

#define NW 16         // waves per scan block (13 compute + 3 helper)
#define NCW 13        // compute waves
#define MPW 4         // memory slots per compute wave (52 total, 50 real)
#define WIN 8         // scan steps per window
#define NFW 63        // compute windows (63*8 = 504 >= 500)

// Workspace layout (in floats)
#define OFF_ATTN   0                        // [1001][64] attn rows, cols 50..63 = 0
#define OFF_SQ     (OFF_ATTN + NQ1*64)      // [1001][64] q_embed @ Ws[64:128]
#define OFF_EAD    (OFF_SQ   + NQ1*64)      // [5005][128] interleaved (e,ad) per v
#define OFF_WST    (OFF_EAD  + NQ1*KK*128)  // [50][64] transposed top of Ws
#define OFF_WCT    (OFF_WST  + SD*64)       // [5][50] transposed Wc (pad to 256)
#define OFF_READS  (OFF_WCT  + 256)         // [512*500][64]

#define LGKM_BARRIER() asm volatile("s_waitcnt lgkmcnt(0)\n\ts_barrier" ::: "memory")

// ---------------- kernel 1: all tables (qtab softmax+Sq, transposes, ead) ----------------
__global__ __launch_bounds__(64) void k_tabs(
    const float* __restrict__ qtab, const float* __restrict__ itab,
    const float* __restrict__ keymem,
    const float* __restrict__ Wv, const float* __restrict__ bv,
    const float* __restrict__ We, const float* __restrict__ be,
    const float* __restrict__ Wa, const float* __restrict__ ba,
    const float* __restrict__ Ws, const float* __restrict__ Wc,
    float* __restrict__ attn_tab, float* __restrict__ sq_tab,
    float* __restrict__ ead_tab, float* __restrict__ WsT, float* __restrict__ WcT) {
  const int bid = blockIdx.x;
  const int t = threadIdx.x;

  if (bid < NQ1) {  // ---- per-question: attn softmax row + sq row ----
    const int q = bid;
    __shared__ float qe[64];
    qe[t] = qtab[q * KD + t];
    __syncthreads();

    float dot = 0.f;
    if (t < MM) {
#pragma unroll
      for (int i = 0; i < KD; ++i) dot = fmaf(qe[i], keymem[t * KD + i], dot);
    }
    float xv = (t < MM) ? dot : -1e30f;
#pragma unroll
    for (int off = 32; off; off >>= 1) xv = fmaxf(xv, __shfl_xor(xv, off));
    float p = (t < MM) ? __expf(dot - xv) : 0.f;
    float sum = p;
#pragma unroll
    for (int off = 32; off; off >>= 1) sum += __shfl_xor(sum, off);
    attn_tab[q * 64 + t] = p / sum;   // pad lanes (t>=50) write 0

    float sq = 0.f;
    if (t < SD) {
#pragma unroll
      for (int i = 0; i < KD; ++i) sq = fmaf(qe[i], Ws[(64 + i) * SD + t], sq);
    }
    sq_tab[q * 64 + t] = (t < SD) ? sq : 0.f;
    return;
  }

  if (bid == NQ1) {  // ---- transposes ----
    for (int idx = t; idx < 64 * SD; idx += 64) {
      int i = idx / SD, j = idx % SD;
      WsT[j * 64 + i] = Ws[idx];
    }
    for (int idx = t; idx < SD * KK; idx += 64) {
      int j = idx / KK, c = idx % KK;
      WcT[c * SD + j] = Wc[idx];
    }
    return;
  }

  // ---- per-(q,r) erase/add, interleaved ----
  const int qr = bid - (NQ1 + 1);
  const int q = qr / KK, r = qr % KK;
  const int v = t;
  __shared__ float item[64];
  __shared__ float ves[64];
  item[v] = itab[q * KD + v];
  __syncthreads();

  float ve = bv[v];
#pragma unroll
  for (int i = 0; i < KD; ++i) ve = fmaf(item[i], Wv[i * VD + v], ve);
#pragma unroll
  for (int k = 0; k < KK; ++k) {
    float rf = fmaxf(0.f, 1.f - fabsf((float)k - (float)r) * 0.25f);
    ve = fmaf(rf, Wv[(KD + k) * VD + v], ve);
  }
  ves[v] = ve;
  __syncthreads();

  float se = be[v], sa = ba[v];
#pragma unroll
  for (int i = 0; i < VD; ++i) {
    float x = ves[i];
    se = fmaf(x, We[i * VD + v], se);
    sa = fmaf(x, Wa[i * VD + v], sa);
  }
  float ex = __expf(2.f * sa);
  ead_tab[qr * 128 + 2 * v]     = 1.f / (1.f + __expf(-se));
  ead_tab[qr * 128 + 2 * v + 1] = (ex - 1.f) / (ex + 1.f);
}

// ---------------- kernel 2: scan, wave-specialized (13 compute + 3 helper waves) ----------------
__global__ __launch_bounds__(1024, 8) void k_scan(
    const int* __restrict__ qs, const int* __restrict__ rs,
    const float* __restrict__ attn_tab, const float* __restrict__ ead_tab,
    const float* __restrict__ init_vm, float* __restrict__ reads) {
  const int b = blockIdx.x;
  const int tid = threadIdx.x;
  const int w = tid >> 6;       // wave id 0..15
  const int v = tid & 63;       // value column

  __shared__ float red[2][WIN][NCW][64];   // 53248 B partial read sums
  __shared__ float abuf[2][WIN][64];       // 4096 B attn rows (52 used)
  __shared__ float eadbuf[2][WIN][128];    // 8192 B (e,ad) pairs per v
  // total 65536 B

  const int* __restrict__ qb = qs + b * SS;
  const int* __restrict__ rb = rs + b * SS;
  float* __restrict__ outp = reads + (size_t)b * SS * 64;

  // ---- prologue: stage window 0 (all waves) ----
  if (w < 8) {
    int q0 = qb[w];
    abuf[0][w][v] = attn_tab[q0 * 64 + v];
  } else if (w < 16) {
    int row = w - 8;
    int q0 = qb[row], r0 = rb[row];
    float2 tt = *(const float2*)(ead_tab + (q0 * KK + r0) * 128 + 2 * v);
    *(float2*)&eadbuf[0][row][2 * v] = tt;
  }

  float vm[MPW];
  int hoff[6];
  if (w < NCW) {
#pragma unroll
    for (int i = 0; i < MPW; ++i) {
      int m = w * MPW + i;
      vm[i] = (m < MM) ? init_vm[m * VD + v] : 0.f;
    }
  } else {
    const int h = tid - NCW * 64;   // 0..191
#pragma unroll
    for (int j = 0; j < 6; ++j) {
      const int tt = h + 192 * j;
      const int kind = tt >> 9;             // 0=a, 1=ead, 2=skip
      const int row = (tt >> 6) & 7;
      const int col = tt & 63;
      if (kind < 2) {
        int idx = WIN + row;                // window 1 rows
        int q = qb[idx];
        int r = (kind == 1) ? rb[idx] : 0;
        hoff[j] = (kind == 1) ? ((q * KK + r) * 128 + 2 * col) : (q * 64 + col);
      }
    }
  }
  __syncthreads();

#define STEP(kk) {                                                    \
    float4 a = ar[(kk) & 1]; float2 e = ed[(kk) & 1];                 \
    if ((kk) < WIN - 2) {                                             \
      ar[(kk) & 1] = *(const float4*)&abuf[buf][(kk) + 2][w * MPW];   \
      ed[(kk) & 1] = *(const float2*)&eadbuf[buf][(kk) + 2][2 * v];   \
    }                                                                 \
    float acc0, acc1;                                                 \
    acc0 = a.x * vm[0];                                               \
    vm[0] = fmaf(a.x, fmaf(-e.x, vm[0], e.y), vm[0]);                 \
    acc1 = a.y * vm[1];                                               \
    vm[1] = fmaf(a.y, fmaf(-e.x, vm[1], e.y), vm[1]);                 \
    acc0 = fmaf(a.z, vm[2], acc0);                                    \
    vm[2] = fmaf(a.z, fmaf(-e.x, vm[2], e.y), vm[2]);                 \
    acc1 = fmaf(a.w, vm[3], acc1);                                    \
    vm[3] = fmaf(a.w, fmaf(-e.x, vm[3], e.y), vm[3]);                 \
    red[buf][kk][w][v] = acc0 + acc1;                                 \
  }

  for (int wi = 0; wi < NFW + 1; ++wi) {
    const int buf = wi & 1;

    if (w < NCW) {
      // ================= compute waves: pure LDS + FMA =================
      if (wi < NFW) {
        float4 ar[2]; float2 ed[2];
        ar[0] = *(const float4*)&abuf[buf][0][w * MPW];
        ar[1] = *(const float4*)&abuf[buf][1][w * MPW];
        ed[0] = *(const float2*)&eadbuf[buf][0][2 * v];
        ed[1] = *(const float2*)&eadbuf[buf][1][2 * v];
        STEP(0); STEP(1); STEP(2); STEP(3);
        STEP(4); STEP(5); STEP(6); STEP(7);
      }
    } else {
      // ================= helper waves: gather + flush + prefetch =================
      const int h = tid - NCW * 64;
      const bool stg = (wi <= NFW - 2);     // stage windows 1..62
      float t0[6], t1[6];

      // 1) gather issue for window wi+1 (offsets prefetched 2 windows ago)
      if (stg) {
#pragma unroll
        for (int j = 0; j < 6; ++j) {
          const int tt = h + 192 * j;
          const int kind = tt >> 9;
          if (kind == 0) {
            t0[j] = attn_tab[hoff[j]];
          } else if (kind == 1) {
            float2 p2 = *(const float2*)(ead_tab + hoff[j]);
            t0[j] = p2.x; t1[j] = p2.y;
          }
        }
      }

      // 2) flush window wi-1 (red partials, global store stays in flight)
      if (wi >= 1) {
        const int fw = wi - 1;
        const int pb = fw & 1;
        const int lim = (fw == NFW - 1) ? (SS - (NFW - 1) * WIN) * 64 : WIN * 64;
#pragma unroll
        for (int jj = 0; jj < 3; ++jj) {
          const int idx = h + 192 * jj;
          if (idx < lim) {
            const int rr = idx >> 6, cc = idx & 63;
            float s = 0.f;
#pragma unroll
            for (int wv = 0; wv < NCW; ++wv) s += red[pb][rr][wv][cc];
            outp[((size_t)fw * WIN + rr) * 64 + cc] = s;
          }
        }
      }

      // 3) prefetch gather offsets for window wi+2
      if (wi <= NFW - 3) {
#pragma unroll
        for (int j = 0; j < 6; ++j) {
          const int tt = h + 192 * j;
          const int kind = tt >> 9;
          const int row = (tt >> 6) & 7;
          const int col = tt & 63;
          if (kind < 2) {
            int idx = (wi + 2) * WIN + row;
            idx = (idx < SS) ? idx : (SS - 1);
            int q = qb[idx];
            int r = (kind == 1) ? rb[idx] : 0;
            hoff[j] = (kind == 1) ? ((q * KK + r) * 128 + 2 * col) : (q * 64 + col);
          }
        }
      }

      // 4) staging writes into the other buffer
      if (stg) {
        const int nb = buf ^ 1;
#pragma unroll
        for (int j = 0; j < 6; ++j) {
          const int tt = h + 192 * j;
          const int kind = tt >> 9;
          const int row = (tt >> 6) & 7;
          const int col = tt & 63;
          if (kind == 0) {
            abuf[nb][row][col] = t0[j];
          } else if (kind == 1) {
            *(float2*)&eadbuf[nb][row][2 * col] = make_float2(t0[j], t1[j]);
          }
        }
      }
    }

    // window barrier: LDS drain only; all VMEM stays in flight
    LGKM_BARRIER();
  }
#undef STEP
}

// ---------------- kernel 3: summary + logits + softmax ----------------
__global__ __launch_bounds__(64) void k_out(
    const float* __restrict__ reads, const int* __restrict__ qs,
    const float* __restrict__ sq_tab, const float* __restrict__ WsT,
    const float* __restrict__ bs, const float* __restrict__ WcT,
    const float* __restrict__ bc,
    float* __restrict__ out_logits, float* __restrict__ out_probs) {
  __shared__ float xs[64 * 65];
  const int lane = threadIdx.x;
  const long rowbase = (long)blockIdx.x * 64;
  const float* __restrict__ src = reads + rowbase * 64;

#pragma unroll 8
  for (int it = 0; it < 64; ++it)
    xs[it * 65 + lane] = src[it * 64 + lane];
  __syncthreads();

  float x[64];
#pragma unroll
  for (int i = 0; i < 64; ++i) x[i] = xs[lane * 65 + i];

  const long row = rowbase + lane;
  const int q = qs[row];
  const float* __restrict__ sqrow = sq_tab + (long)q * 64;

  float sm[SD];
#pragma unroll
  for (int j = 0; j < SD; ++j) {
    float acc = bs[j] + sqrow[j];
    const float* __restrict__ wrow = WsT + j * 64;  // uniform -> s_load
#pragma unroll
    for (int i = 0; i < 64; ++i) acc = fmaf(x[i], wrow[i], acc);
    float ex = __expf(2.f * acc);
    sm[j] = (ex - 1.f) / (ex + 1.f);
  }

  float lg[KK];
#pragma unroll
  for (int c = 0; c < KK; ++c) {
    float acc = bc[c];
    const float* __restrict__ wrow = WcT + c * SD;  // uniform -> s_load
#pragma unroll
    for (int j = 0; j < SD; ++j) acc = fmaf(sm[j], wrow[j], acc);
    lg[c] = acc;
  }

  float mx = lg[0];
#pragma unroll
  for (int c = 1; c < KK; ++c) mx = fmaxf(mx, lg[c]);
  float p[KK], sum = 0.f;
#pragma unroll
  for (int c = 0; c < KK; ++c) { p[c] = __expf(lg[c] - mx); sum += p[c]; }
  float inv = 1.f / sum;
#pragma unroll
  for (int c = 0; c < KK; ++c) {
    out_logits[row * KK + c] = lg[c];
    out_probs[row * KK + c] = p[c] * inv;
  }
}

extern "C" void kernel_launch(void* const* d_in, const int* in_sizes, int n_in,
                              void* d_out, int out_size, void* d_ws, size_t ws_size,
                              hipStream_t stream) {
  const int*   questions  = (const int*)  d_in[0];
  const int*   responses  = (const int*)  d_in[1];
  const float* q_table    = (const float*)d_in[2];
  const float* item_table = (const float*)d_in[3];
  const float* Wv         = (const float*)d_in[4];
  const float* bv         = (const float*)d_in[5];
  const float* key_mem    = (const float*)d_in[6];
  const float* init_vm    = (const float*)d_in[7];
  const float* We         = (const float*)d_in[8];
  const float* be         = (const float*)d_in[9];
  const float* Wa         = (const float*)d_in[10];
  const float* ba         = (const float*)d_in[11];
  const float* Ws         = (const float*)d_in[12];
  const float* bs         = (const float*)d_in[13];
  const float* Wc         = (const float*)d_in[14];
  const float* bc         = (const float*)d_in[15];

  float* ws       = (float*)d_ws;
  float* attn_tab = ws + OFF_ATTN;
  float* sq_tab   = ws + OFF_SQ;
  float* ead_tab  = ws + OFF_EAD;
  float* WsT      = ws + OFF_WST;
  float* WcT      = ws + OFF_WCT;
  float* reads    = ws + OFF_READS;

  float* out_logits = (float*)d_out;
  float* out_probs  = out_logits + (size_t)BB * SS * KK;

  hipLaunchKernelGGL(k_tabs, dim3(NQ1 + 1 + NQ1 * KK), dim3(64), 0, stream,
                     q_table, item_table, key_mem, Wv, bv, We, be, Wa, ba, Ws, Wc,
                     attn_tab, sq_tab, ead_tab, WsT, WcT);
  hipLaunchKernelGGL(k_scan, dim3(BB), dim3(NW * 64), 0, stream,
                     questions, responses, attn_tab, ead_tab, init_vm, reads);
  hipLaunchKernelGGL(k_out, dim3(BB * SS / 64), dim3(64), 0, stream,
                     reads, questions, sq_tab, WsT, bs, WcT, bc,
                     out_logits, out_probs);
}

// Round 7
// 243.405 us; speedup vs baseline: 1.6294x; 1.6294x over previous
//
#include <hip/hip_runtime.h>
#include <hip/hip_bf16.h>
#include <math.h>

// Problem constants
#define NQ1 1001      // NQ+1 rows in embed tables
#define KK 5
#define MM 50
#define KD 64
#define VD 64
#define SD 50
#define BB 512
#define SS 500

#define NW 8          // waves per scan block
#define WIN 8         // scan steps per window
#define NWIN 62       // full windows (62*8 = 496; tail = 4 steps)

// Workspace layout (in floats)
#define OFF_ATTN   0                        // [1001][64] attn rows, cols 50..63 = 0
#define OFF_SQ     (OFF_ATTN + NQ1*64)      // [1001][64] q_embed @ Ws[64:128]
#define OFF_EAD    (OFF_SQ   + NQ1*64)      // [5005][128] interleaved (e,ad) per v
#define OFF_WST    (OFF_EAD  + NQ1*KK*128)  // [50][64] transposed top of Ws
#define OFF_WCT    (OFF_WST  + SD*64)       // [5][50] transposed Wc (pad to 256)
#define OFF_READS  (OFF_WCT  + 256)         // [512*500][64]

#define LGKM_BARRIER() asm volatile("s_waitcnt lgkmcnt(0)\n\ts_barrier" ::: "memory")

// ---------------- kernel 1: all tables (qtab softmax+Sq, transposes, ead) ----------------
__global__ __launch_bounds__(64) void k_tabs(
    const float* __restrict__ qtab, const float* __restrict__ itab,
    const float* __restrict__ keymem,
    const float* __restrict__ Wv, const float* __restrict__ bv,
    const float* __restrict__ We, const float* __restrict__ be,
    const float* __restrict__ Wa, const float* __restrict__ ba,
    const float* __restrict__ Ws, const float* __restrict__ Wc,
    float* __restrict__ attn_tab, float* __restrict__ sq_tab,
    float* __restrict__ ead_tab, float* __restrict__ WsT, float* __restrict__ WcT) {
  const int bid = blockIdx.x;
  const int t = threadIdx.x;

  if (bid < NQ1) {  // ---- per-question: attn softmax row + sq row ----
    const int q = bid;
    __shared__ float qe[64];
    qe[t] = qtab[q * KD + t];
    __syncthreads();

    float dot = 0.f;
    if (t < MM) {
#pragma unroll
      for (int i = 0; i < KD; ++i) dot = fmaf(qe[i], keymem[t * KD + i], dot);
    }
    float xv = (t < MM) ? dot : -1e30f;
#pragma unroll
    for (int off = 32; off; off >>= 1) xv = fmaxf(xv, __shfl_xor(xv, off));
    float p = (t < MM) ? __expf(dot - xv) : 0.f;
    float sum = p;
#pragma unroll
    for (int off = 32; off; off >>= 1) sum += __shfl_xor(sum, off);
    attn_tab[q * 64 + t] = p / sum;   // pad lanes (t>=50) write 0

    float sq = 0.f;
    if (t < SD) {
#pragma unroll
      for (int i = 0; i < KD; ++i) sq = fmaf(qe[i], Ws[(64 + i) * SD + t], sq);
    }
    sq_tab[q * 64 + t] = (t < SD) ? sq : 0.f;
    return;
  }

  if (bid == NQ1) {  // ---- transposes ----
    for (int idx = t; idx < 64 * SD; idx += 64) {
      int i = idx / SD, j = idx % SD;
      WsT[j * 64 + i] = Ws[idx];
    }
    for (int idx = t; idx < SD * KK; idx += 64) {
      int j = idx / KK, c = idx % KK;
      WcT[c * SD + j] = Wc[idx];
    }
    return;
  }

  // ---- per-(q,r) erase/add, interleaved ----
  const int qr = bid - (NQ1 + 1);
  const int q = qr / KK, r = qr % KK;
  const int v = t;
  __shared__ float item[64];
  __shared__ float ves[64];
  item[v] = itab[q * KD + v];
  __syncthreads();

  float ve = bv[v];
#pragma unroll
  for (int i = 0; i < KD; ++i) ve = fmaf(item[i], Wv[i * VD + v], ve);
#pragma unroll
  for (int k = 0; k < KK; ++k) {
    float rf = fmaxf(0.f, 1.f - fabsf((float)k - (float)r) * 0.25f);
    ve = fmaf(rf, Wv[(KD + k) * VD + v], ve);
  }
  ves[v] = ve;
  __syncthreads();

  float se = be[v], sa = ba[v];
#pragma unroll
  for (int i = 0; i < VD; ++i) {
    float x = ves[i];
    se = fmaf(x, We[i * VD + v], se);
    sa = fmaf(x, Wa[i * VD + v], sa);
  }
  float ex = __expf(2.f * sa);
  ead_tab[qr * 128 + 2 * v]     = 1.f / (1.f + __expf(-se));
  ead_tab[qr * 128 + 2 * v + 1] = (ex - 1.f) / (ex + 1.f);
}

// ---------------- kernel 2: scan, v-split (block = batch x v-half), window-LDS-staged ----------------
__global__ __launch_bounds__(512, 8) void k_scan(
    const int* __restrict__ qs, const int* __restrict__ rs,
    const float* __restrict__ attn_tab, const float* __restrict__ ead_tab,
    const float* __restrict__ init_vm, float* __restrict__ reads) {
  const int bid = blockIdx.x;
  const int b = bid >> 1;
  const int vh = bid & 1;          // v-half (columns vh*32 .. vh*32+31)
  const int tid = threadIdx.x;
  const int w = tid >> 6;          // wave id 0..7 (m-slots w*8 .. w*8+7)
  const int lane = tid & 63;
  const int vl = lane & 31;        // local v column
  const int mh = lane >> 5;        // m sub-half
  const int gv = vh * 32 + vl;     // global v column
  const int mfirst = w * 8 + mh * 4;

  __shared__ float red[2][WIN][NW][32];    // 16384 B per-wave column sums
  __shared__ float abuf[2][WIN][64];       // 4096 B attn rows (m-indexed, full)
  __shared__ float eadbuf[2][WIN][64];     // 4096 B (e,ad) pairs, 32 local cols

  const int* __restrict__ qb = qs + b * SS;
  const int* __restrict__ rb = rs + b * SS;
  float* __restrict__ outp = reads + (size_t)b * SS * 64 + vh * 32;

  // ---- prologue: stage window 0 directly; preload q/r for window 1 ----
  {
    int q0 = qb[w], r0 = rb[w];
    abuf[0][w][lane] = attn_tab[q0 * 64 + lane];
    if (lane < 32) {
      float2 tt = *(const float2*)(ead_tab + (q0 * KK + r0) * 128 + 2 * gv);
      *(float2*)&eadbuf[0][w][2 * vl] = tt;
    }
  }
  int q1 = qb[WIN + w], r1 = rb[WIN + w];    // window-1 indices (row w)

  float vm[4];
#pragma unroll
  for (int i = 0; i < 4; ++i) {
    int m = mfirst + i;
    vm[i] = (m < MM) ? init_vm[m * VD + gv] : 0.f;
  }
  __syncthreads();

#define PRELOAD(buf_) {                                         \
    ar[0] = *(const float4*)&abuf[buf_][0][mfirst];             \
    ar[1] = *(const float4*)&abuf[buf_][1][mfirst];             \
    ed[0] = *(const float2*)&eadbuf[buf_][0][2 * vl];           \
    ed[1] = *(const float2*)&eadbuf[buf_][1][2 * vl];           \
  }

#define STEP(buf_, kk) {                                        \
    float4 a = ar[(kk) & 1]; float2 e = ed[(kk) & 1];           \
    if ((kk) < WIN - 2) {                                       \
      ar[(kk) & 1] = *(const float4*)&abuf[buf_][(kk) + 2][mfirst];   \
      ed[(kk) & 1] = *(const float2*)&eadbuf[buf_][(kk) + 2][2 * vl]; \
    }                                                           \
    float acc0, acc1;                                           \
    acc0 = a.x * vm[0];                                         \
    vm[0] = fmaf(a.x, fmaf(-e.x, vm[0], e.y), vm[0]);           \
    acc1 = a.y * vm[1];                                         \
    vm[1] = fmaf(a.y, fmaf(-e.x, vm[1], e.y), vm[1]);           \
    acc0 = fmaf(a.z, vm[2], acc0);                              \
    vm[2] = fmaf(a.z, fmaf(-e.x, vm[2], e.y), vm[2]);           \
    acc1 = fmaf(a.w, vm[3], acc1);                              \
    vm[3] = fmaf(a.w, fmaf(-e.x, vm[3], e.y), vm[3]);           \
    float accs = (acc0 + acc1);                                 \
    accs += __shfl_xor(accs, 32, 64);                           \
    red[buf_][kk][w][vl] = accs;  /* mh pair: same addr, same value */ \
  }

#define FLUSH(fw_, nrows_) {                                    \
    const int pb = (fw_) & 1;                                   \
    if (tid < 32 * (nrows_)) {                                  \
      const int rr = tid >> 5, cc = tid & 31;                   \
      float s = 0.f;                                            \
      _Pragma("unroll")                                         \
      for (int wv = 0; wv < NW; ++wv) s += red[pb][rr][wv][cc]; \
      outp[(size_t)((fw_) * WIN + rr) * 64 + cc] = s;           \
    }                                                           \
  }

  for (int wi = 0; wi < NWIN; ++wi) {
    const int buf = wi & 1;
    const int nb = buf ^ 1;

    // 1. preload register rings for steps 0,1 of this window
    float4 ar[2]; float2 ed[2];
    PRELOAD(buf);

    // 2. staging issue for window wi+1 (VMEM; q1/r1 loaded a window ago)
    float a_st = attn_tab[q1 * 64 + lane];
    float2 e_st = make_float2(0.f, 0.f);
    if (lane < 32)
      e_st = *(const float2*)(ead_tab + (q1 * KK + r1) * 128 + 2 * gv);
    int i2 = (wi + 2) * WIN + w;
    i2 = (i2 < SS) ? i2 : (SS - 1);
    int q2 = qb[i2], r2 = rb[i2];

    // 3. flush previous window (store issued after gather loads)
    if (wi > 0) FLUSH(wi - 1, WIN);

    // 4. compute 8 steps (LDS + registers only)
    STEP(buf, 0); STEP(buf, 1); STEP(buf, 2); STEP(buf, 3);
    STEP(buf, 4); STEP(buf, 5); STEP(buf, 6); STEP(buf, 7);

    // 5. staging writes (compiler waits vmcnt for gather data only)
    abuf[nb][w][lane] = a_st;
    if (lane < 32) *(float2*)&eadbuf[nb][w][2 * vl] = e_st;
    q1 = q2; r1 = r2;

    // 6. window barrier: LDS drain only; VMEM stays in flight
    LGKM_BARRIER();
  }

  // ---- tail: window 62 = steps 496..499 (buf 0) ----
  {
    float4 ar[2]; float2 ed[2];
    PRELOAD(0);
    FLUSH(NWIN - 1, WIN);                   // flush window 61
    STEP(0, 0); STEP(0, 1); STEP(0, 2); STEP(0, 3);
    LGKM_BARRIER();
    FLUSH(NWIN, SS - NWIN * WIN);           // 4 tail rows (62&1==0)
  }
#undef PRELOAD
#undef STEP
#undef FLUSH
}

// ---------------- kernel 3: summary + logits + softmax ----------------
__global__ __launch_bounds__(64) void k_out(
    const float* __restrict__ reads, const int* __restrict__ qs,
    const float* __restrict__ sq_tab, const float* __restrict__ WsT,
    const float* __restrict__ bs, const float* __restrict__ WcT,
    const float* __restrict__ bc,
    float* __restrict__ out_logits, float* __restrict__ out_probs) {
  __shared__ float xs[64 * 65];
  const int lane = threadIdx.x;
  const long rowbase = (long)blockIdx.x * 64;
  const float* __restrict__ src = reads + rowbase * 64;

#pragma unroll 8
  for (int it = 0; it < 64; ++it)
    xs[it * 65 + lane] = src[it * 64 + lane];
  __syncthreads();

  float x[64];
#pragma unroll
  for (int i = 0; i < 64; ++i) x[i] = xs[lane * 65 + i];

  const long row = rowbase + lane;
  const int q = qs[row];
  const float* __restrict__ sqrow = sq_tab + (long)q * 64;

  float sm[SD];
#pragma unroll
  for (int j = 0; j < SD; ++j) {
    float acc = bs[j] + sqrow[j];
    const float* __restrict__ wrow = WsT + j * 64;  // uniform -> s_load
#pragma unroll
    for (int i = 0; i < 64; ++i) acc = fmaf(x[i], wrow[i], acc);
    float ex = __expf(2.f * acc);
    sm[j] = (ex - 1.f) / (ex + 1.f);
  }

  float lg[KK];
#pragma unroll
  for (int c = 0; c < KK; ++c) {
    float acc = bc[c];
    const float* __restrict__ wrow = WcT + c * SD;  // uniform -> s_load
#pragma unroll
    for (int j = 0; j < SD; ++j) acc = fmaf(sm[j], wrow[j], acc);
    lg[c] = acc;
  }

  float mx = lg[0];
#pragma unroll
  for (int c = 1; c < KK; ++c) mx = fmaxf(mx, lg[c]);
  float p[KK], sum = 0.f;
#pragma unroll
  for (int c = 0; c < KK; ++c) { p[c] = __expf(lg[c] - mx); sum += p[c]; }
  float inv = 1.f / sum;
#pragma unroll
  for (int c = 0; c < KK; ++c) {
    out_logits[row * KK + c] = lg[c];
    out_probs[row * KK + c] = p[c] * inv;
  }
}

extern "C" void kernel_launch(void* const* d_in, const int* in_sizes, int n_in,
                              void* d_out, int out_size, void* d_ws, size_t ws_size,
                              hipStream_t stream) {
  const int*   questions  = (const int*)  d_in[0];
  const int*   responses  = (const int*)  d_in[1];
  const float* q_table    = (const float*)d_in[2];
  const float* item_table = (const float*)d_in[3];
  const float* Wv         = (const float*)d_in[4];
  const float* bv         = (const float*)d_in[5];
  const float* key_mem    = (const float*)d_in[6];
  const float* init_vm    = (const float*)d_in[7];
  const float* We         = (const float*)d_in[8];
  const float* be         = (const float*)d_in[9];
  const float* Wa         = (const float*)d_in[10];
  const float* ba         = (const float*)d_in[11];
  const float* Ws         = (const float*)d_in[12];
  const float* bs         = (const float*)d_in[13];
  const float* Wc         = (const float*)d_in[14];
  const float* bc         = (const float*)d_in[15];

  float* ws       = (float*)d_ws;
  float* attn_tab = ws + OFF_ATTN;
  float* sq_tab   = ws + OFF_SQ;
  float* ead_tab  = ws + OFF_EAD;
  float* WsT      = ws + OFF_WST;
  float* WcT      = ws + OFF_WCT;
  float* reads    = ws + OFF_READS;

  float* out_logits = (float*)d_out;
  float* out_probs  = out_logits + (size_t)BB * SS * KK;

  hipLaunchKernelGGL(k_tabs, dim3(NQ1 + 1 + NQ1 * KK), dim3(64), 0, stream,
                     q_table, item_table, key_mem, Wv, bv, We, be, Wa, ba, Ws, Wc,
                     attn_tab, sq_tab, ead_tab, WsT, WcT);
  hipLaunchKernelGGL(k_scan, dim3(BB * 2), dim3(NW * 64), 0, stream,
                     questions, responses, attn_tab, ead_tab, init_vm, reads);
  hipLaunchKernelGGL(k_out, dim3(BB * SS / 64), dim3(64), 0, stream,
                     reads, questions, sq_tab, WsT, bs, WcT, bc,
                     out_logits, out_probs);
}